// Round 5
// baseline (288.037 us; speedup 1.0000x reference)
//
#include <hip/hip_runtime.h>
#include <hip/hip_bf16.h>
#include <hip/hip_fp16.h>

typedef _Float16 f16x8 __attribute__((ext_vector_type(8)));
typedef __fp16  h16x2 __attribute__((ext_vector_type(2)));
typedef float f32x4 __attribute__((ext_vector_type(4)));

#define S_LEN 1024
#define DH 64
#define KVB 64
#define NIT 16
#define KROW 72   // padded K/V LDS row (elements)
#define PROW 40   // padded P row (32 + 8)

__device__ __forceinline__ unsigned rotl(unsigned x, unsigned r) {
  // guaranteed single v_alignbit_b32
  return __builtin_amdgcn_alignbit(x, x, 32u - r);
}

// JAX threefry2x32, key=(0,42), counts=(0,e) [threefry_partitionable].
// draw = x0 ^ x1; keep = top bit == 0 (uniform < 0.5).
__device__ __forceinline__ bool keep_bit(unsigned e) {
  const unsigned ks1 = 42u;
  const unsigned ks2 = 0x1BD11BF0u;  // 0 ^ 42 ^ 0x1BD11BDA
  unsigned x0 = 0u;
  unsigned x1 = e + ks1;
#define TFR(Ra,Rb,Rc,Rd) \
  x0 += x1; x1 = rotl(x1, Ra); x1 ^= x0; \
  x0 += x1; x1 = rotl(x1, Rb); x1 ^= x0; \
  x0 += x1; x1 = rotl(x1, Rc); x1 ^= x0; \
  x0 += x1; x1 = rotl(x1, Rd); x1 ^= x0;
  TFR(13u,15u,26u, 6u)  x0 += ks1; x1 += ks2 + 1u;
  TFR(17u,29u,16u,24u)  x0 += ks2; x1 += 2u;
  TFR(13u,15u,26u, 6u)  /* +0 */   x1 += ks1 + 3u;
  TFR(17u,29u,16u,24u)  x0 += ks1; x1 += ks2 + 4u;
  TFR(13u,15u,26u, 6u)  x0 += ks2; x1 += 5u;
#undef TFR
  return ((x0 ^ x1) >> 31) == 0u;
}

__device__ __forceinline__ f16x8 pk8(f32x4 a, f32x4 b) {
  h16x2 p0 = __builtin_amdgcn_cvt_pkrtz(a[0], a[1]);
  h16x2 p1 = __builtin_amdgcn_cvt_pkrtz(a[2], a[3]);
  h16x2 p2 = __builtin_amdgcn_cvt_pkrtz(b[0], b[1]);
  h16x2 p3 = __builtin_amdgcn_cvt_pkrtz(b[2], b[3]);
  f16x8 r;
  r[0]=(_Float16)p0[0]; r[1]=(_Float16)p0[1]; r[2]=(_Float16)p1[0]; r[3]=(_Float16)p1[1];
  r[4]=(_Float16)p2[0]; r[5]=(_Float16)p2[1]; r[6]=(_Float16)p3[0]; r[7]=(_Float16)p3[1];
  return r;
}

__global__ __launch_bounds__(512)
void attn_dropout_kernel(const float* __restrict__ Q, const float* __restrict__ K,
                         const float* __restrict__ V, float* __restrict__ out) {
  // One block: one (b,h), 64 q-rows, 8 waves.
  // Wave pair (w, w+4): same 16 q-rows, k-columns split 32/32; merged at end.
  __shared__ __align__(16) char smem[64*KROW*2*2 + 8*16*PROW*2];  // 28672 B
  _Float16* Kl = (_Float16*)smem;        // [64][KROW]  row-major [k][d]
  _Float16* Vt = Kl + 64*KROW;           // [64][KROW]  transposed [d][k]
  _Float16* Pl = Vt + 64*KROW;           // [8][16][PROW] wave-private P

  const unsigned bh   = blockIdx.x >> 4;
  const unsigned q0   = (blockIdx.x & 15u) * 64u;
  const unsigned tid  = threadIdx.x;
  const unsigned w    = tid >> 6;
  const unsigned lane = tid & 63u;
  const unsigned g    = lane >> 4;       // 0..3
  const unsigned ln   = lane & 15u;      // 0..15
  const unsigned qw   = q0 + (w & 3u) * 16u;
  const unsigned koff = (w >> 2) * 32u;  // this wave's k-column half

  // ---- Q fragments (A-frag: row=ln, k(d)=g*8+j), two d-halves ----
  f16x8 Qa0, Qa1;
  {
    const float* Qp = Q + (size_t)(bh * S_LEN + qw + ln) * DH + g * 8;
    Qa0 = pk8(*(const f32x4*)(Qp),      *(const f32x4*)(Qp + 4));
    Qa1 = pk8(*(const f32x4*)(Qp + 32), *(const f32x4*)(Qp + 36));
  }

  float mrun[4], lrun[4];
  f32x4 accO[4];
#pragma unroll
  for (int r = 0; r < 4; ++r) { mrun[r] = -1e30f; lrun[r] = 0.0f; }
#pragma unroll
  for (int n = 0; n < 4; ++n) accO[n] = (f32x4){0.f, 0.f, 0.f, 0.f};

  const unsigned kk = tid >> 3;          // 0..63 staging row
  const unsigned dg = (tid & 7u) * 8u;   // element offset, 8 floats/thread

  for (int t = 0; t < NIT; ++t) {
    __syncthreads();
    // ---- stage K tile [k][d] fp16 ----
    {
      const float* Kp = K + (size_t)(bh * S_LEN + t * KVB + kk) * DH + dg;
      *(f16x8*)&Kl[kk * KROW + dg] = pk8(*(const f32x4*)Kp, *(const f32x4*)(Kp + 4));
    }
    // ---- stage V tile transposed [d][k] ----
    {
      const float* Vp = V + (size_t)(bh * S_LEN + t * KVB + kk) * DH + dg;
      f32x4 v0 = *(const f32x4*)Vp;
      f32x4 v1 = *(const f32x4*)(Vp + 4);
#pragma unroll
      for (int i = 0; i < 4; ++i) {
        Vt[(dg + i) * KROW + kk]     = (_Float16)v0[i];
        Vt[(dg + 4 + i) * KROW + kk] = (_Float16)v1[i];
      }
    }
    __syncthreads();

    // ---- S = Q K^T : 16 q-rows x 32 k-cols ----
    f32x4 sc[2];
#pragma unroll
    for (int nt = 0; nt < 2; ++nt) {
      const unsigned krow = koff + nt * 16 + ln;
      f16x8 kb0 = *(const f16x8*)&Kl[krow * KROW + g * 8];
      f16x8 kb1 = *(const f16x8*)&Kl[krow * KROW + 32 + g * 8];
      f32x4 a = (f32x4){0.f, 0.f, 0.f, 0.f};
      a = __builtin_amdgcn_mfma_f32_16x16x32_f16(Qa0, kb0, a, 0, 0, 0);
      a = __builtin_amdgcn_mfma_f32_16x16x32_f16(Qa1, kb1, a, 0, 0, 0);
      sc[nt] = a;
    }

    // ---- dropout (threefry) : q = qw+g*4+r, k = t*64+koff+nt*16+ln ----
    float sm[2][4];
#pragma unroll
    for (int nt = 0; nt < 2; ++nt) {
#pragma unroll
      for (int r = 0; r < 4; ++r) {
        unsigned q  = qw + g * 4 + r;
        unsigned kg = (unsigned)t * KVB + koff + nt * 16 + ln;
        unsigned e  = (bh << 20) + (q << 10) + kg;
        float s2 = sc[nt][r] * 2.0f;
        sm[nt][r] = keep_bit(e) ? s2 : 0.0f;   // dropped -> 0, stays in softmax
      }
    }

    // ---- online softmax over this wave's 32 k-cols ----
    float ps[2][4];
#pragma unroll
    for (int r = 0; r < 4; ++r) {
      float mx = fmaxf(sm[0][r], sm[1][r]);
#pragma unroll
      for (int off = 1; off < 16; off <<= 1) mx = fmaxf(mx, __shfl_xor(mx, off));
      float mn  = fmaxf(mrun[r], mx);
      float scl = __expf(mrun[r] - mn);
      mrun[r] = mn;
      float rs = 0.f;
#pragma unroll
      for (int nt = 0; nt < 2; ++nt) {
        float p = __expf(sm[nt][r] - mn);
        ps[nt][r] = p; rs += p;
      }
#pragma unroll
      for (int off = 1; off < 16; off <<= 1) rs += __shfl_xor(rs, off);
      lrun[r] = lrun[r] * scl + rs;
#pragma unroll
      for (int n = 0; n < 4; ++n) accO[n][r] *= scl;
    }

    // ---- P -> wave-private LDS (re-layout for PV A-frag) ----
#pragma unroll
    for (int nt = 0; nt < 2; ++nt)
#pragma unroll
      for (int r = 0; r < 4; ++r)
        Pl[(w * 16 + g * 4 + r) * PROW + nt * 16 + ln] = (_Float16)ps[nt][r];

    // ---- O += P V  (K-dim = 32 = one MFMA) ----
    f16x8 Pa = *(const f16x8*)&Pl[(w * 16 + ln) * PROW + g * 8];
#pragma unroll
    for (int nd = 0; nd < 4; ++nd) {
      f16x8 vb = *(const f16x8*)&Vt[(nd * 16 + ln) * KROW + koff + g * 8];
      accO[nd] = __builtin_amdgcn_mfma_f32_16x16x32_f16(Pa, vb, accO[nd], 0, 0, 0);
    }
  }

  // ---- merge wave pairs (w, w+4) and write out ----
  float* Om = (float*)smem;              // [64][68]  (pair_q rows, padded)
  float* Ml = Om + 64 * 68;              // [64][2]
  __syncthreads();
  if (w >= 4) {
    const unsigned pq = (w & 3u) * 16u;
#pragma unroll
    for (int nd = 0; nd < 4; ++nd)
#pragma unroll
      for (int r = 0; r < 4; ++r)
        Om[(pq + g * 4 + r) * 68 + nd * 16 + ln] = accO[nd][r];
    if (ln == 0) {
#pragma unroll
      for (int r = 0; r < 4; ++r) {
        Ml[(pq + g * 4 + r) * 2 + 0] = mrun[r];
        Ml[(pq + g * 4 + r) * 2 + 1] = lrun[r];
      }
    }
  }
  __syncthreads();
  if (w < 4) {
    float e1[4], e2[4], lf[4];
#pragma unroll
    for (int r = 0; r < 4; ++r) {
      const unsigned pq = w * 16 + g * 4 + r;
      float m2 = Ml[pq * 2 + 0];
      float l2 = Ml[pq * 2 + 1];
      float m  = fmaxf(mrun[r], m2);
      e1[r] = __expf(mrun[r] - m);
      e2[r] = __expf(m2 - m);
      lf[r] = lrun[r] * e1[r] + l2 * e2[r];
    }
#pragma unroll
    for (int nd = 0; nd < 4; ++nd)
#pragma unroll
      for (int r = 0; r < 4; ++r) {
        const unsigned pq = w * 16 + g * 4 + r;
        float o = accO[nd][r] * e1[r] + Om[pq * 68 + nd * 16 + ln] * e2[r];
        out[(size_t)(bh * S_LEN + q0 + pq) * DH + nd * 16 + ln] = o / lf[r];
      }
  }
}

extern "C" void kernel_launch(void* const* d_in, const int* in_sizes, int n_in,
                              void* d_out, int out_size, void* d_ws, size_t ws_size,
                              hipStream_t stream) {
  const float* Q = (const float*)d_in[0];
  const float* K = (const float*)d_in[1];
  const float* V = (const float*)d_in[2];
  float* out = (float*)d_out;
  dim3 grid(64 * 16);   // (b*16+h) * 16 q-tiles
  dim3 block(512);
  hipLaunchKernelGGL(attn_dropout_kernel, grid, block, 0, stream, Q, K, V, out);
}

// Round 7
// 248.765 us; speedup vs baseline: 1.1579x; 1.1579x over previous
//
#include <hip/hip_runtime.h>
#include <hip/hip_bf16.h>
#include <hip/hip_fp16.h>

typedef _Float16 f16x8 __attribute__((ext_vector_type(8)));
typedef __fp16  h16x2 __attribute__((ext_vector_type(2)));
typedef float f32x4 __attribute__((ext_vector_type(4)));

#define S_LEN 1024
#define DH 64
#define KVB 64
#define NIT 16
#define KROW 72   // padded LDS row (elements)

__device__ __forceinline__ unsigned rotl(unsigned x, unsigned r) {
  return __builtin_amdgcn_alignbit(x, x, 32u - r);  // single v_alignbit_b32
}

// JAX threefry2x32, key=(0,42), counts=(0,e) [threefry_partitionable].
// draw = x0 ^ x1; keep = top bit == 0 (uniform < 0.5).
__device__ __forceinline__ bool keep_bit(unsigned e) {
  const unsigned ks1 = 42u;
  const unsigned ks2 = 0x1BD11BF0u;  // 0 ^ 42 ^ 0x1BD11BDA
  unsigned x0 = 0u;
  unsigned x1 = e + ks1;
#define TFR(Ra,Rb,Rc,Rd) \
  x0 += x1; x1 = rotl(x1, Ra); x1 ^= x0; \
  x0 += x1; x1 = rotl(x1, Rb); x1 ^= x0; \
  x0 += x1; x1 = rotl(x1, Rc); x1 ^= x0; \
  x0 += x1; x1 = rotl(x1, Rd); x1 ^= x0;
  TFR(13u,15u,26u, 6u)  x0 += ks1; x1 += ks2 + 1u;
  TFR(17u,29u,16u,24u)  x0 += ks2; x1 += 2u;
  TFR(13u,15u,26u, 6u)  /* +0 */   x1 += ks1 + 3u;
  TFR(17u,29u,16u,24u)  x0 += ks1; x1 += ks2 + 4u;
  TFR(13u,15u,26u, 6u)  x0 += ks2; x1 += 5u;
#undef TFR
  return ((x0 ^ x1) >> 31) == 0u;
}

__device__ __forceinline__ f16x8 pk8(f32x4 a, f32x4 b) {
  h16x2 p0 = __builtin_amdgcn_cvt_pkrtz(a[0], a[1]);
  h16x2 p1 = __builtin_amdgcn_cvt_pkrtz(a[2], a[3]);
  h16x2 p2 = __builtin_amdgcn_cvt_pkrtz(b[0], b[1]);
  h16x2 p3 = __builtin_amdgcn_cvt_pkrtz(b[2], b[3]);
  f16x8 r;
  r[0]=(_Float16)p0[0]; r[1]=(_Float16)p0[1]; r[2]=(_Float16)p1[0]; r[3]=(_Float16)p1[1];
  r[4]=(_Float16)p2[0]; r[5]=(_Float16)p2[1]; r[6]=(_Float16)p3[0]; r[7]=(_Float16)p3[1];
  return r;
}

__global__ __launch_bounds__(256)
void attn_dropout_kernel(const float* __restrict__ Q, const float* __restrict__ K,
                         const float* __restrict__ V, float* __restrict__ out) {
  // R1 structure: one block = one (b,h) x 64 q-rows; 4 waves x 16 q-rows,
  // each wave covers all 64 k-cols. + T14 reg-prefetch of next K/V tile.
  __shared__ _Float16 Kl[KVB][KROW];      // [k][d]
  __shared__ _Float16 Vt[DH][KROW];       // [d][k] transposed
  __shared__ _Float16 Pl[4][16][KROW];    // per-wave P tile

  const unsigned bh   = blockIdx.x >> 4;
  const unsigned q0   = (blockIdx.x & 15u) * 64u;
  const unsigned tid  = threadIdx.x;
  const unsigned w    = tid >> 6;
  const unsigned lane = tid & 63u;
  const unsigned g    = lane >> 4;     // 0..3
  const unsigned ln   = lane & 15u;    // 0..15
  const unsigned qw   = q0 + w * 16u;

  // ---- Q fragments, pre-scaled by 2 (folds dropout 1/(1-p) into QK^T) ----
  f16x8 Qa0, Qa1;
  {
    const float* Qp = Q + (size_t)(bh * S_LEN + qw + ln) * DH + g * 8;
    f32x4 a = *(const f32x4*)(Qp)      * 2.0f;
    f32x4 b = *(const f32x4*)(Qp + 4)  * 2.0f;
    f32x4 c = *(const f32x4*)(Qp + 32) * 2.0f;
    f32x4 d = *(const f32x4*)(Qp + 36) * 2.0f;
    Qa0 = pk8(a, b);
    Qa1 = pk8(c, d);
  }

  float mrun[4], lrun[4];
  f32x4 accO[4];
#pragma unroll
  for (int r = 0; r < 4; ++r) { mrun[r] = -1e30f; lrun[r] = 0.0f; }
#pragma unroll
  for (int n = 0; n < 4; ++n) accO[n] = (f32x4){0.f, 0.f, 0.f, 0.f};

  const unsigned kk  = tid >> 2;          // 0..63 staging row
  const unsigned dgf = (tid & 3u) * 16u;  // 16 floats per thread

  // ---- prologue: prefetch tile 0 into registers ----
  f32x4 kr0, kr1, kr2, kr3, vr0, vr1, vr2, vr3;
  {
    const float* Kp = K + (size_t)(bh * S_LEN + kk) * DH + dgf;
    kr0 = *(const f32x4*)(Kp);  kr1 = *(const f32x4*)(Kp + 4);
    kr2 = *(const f32x4*)(Kp + 8); kr3 = *(const f32x4*)(Kp + 12);
    const float* Vp = V + (size_t)(bh * S_LEN + kk) * DH + dgf;
    vr0 = *(const f32x4*)(Vp);  vr1 = *(const f32x4*)(Vp + 4);
    vr2 = *(const f32x4*)(Vp + 8); vr3 = *(const f32x4*)(Vp + 12);
  }

  for (int t = 0; t < NIT; ++t) {
    __syncthreads();   // previous tile fully consumed
    // ---- write staged regs (tile t) to LDS ----
    *(f16x8*)&Kl[kk][dgf]     = pk8(kr0, kr1);
    *(f16x8*)&Kl[kk][dgf + 8] = pk8(kr2, kr3);
#pragma unroll
    for (int i = 0; i < 4; ++i) {
      Vt[dgf +  0 + i][kk] = (_Float16)vr0[i];
      Vt[dgf +  4 + i][kk] = (_Float16)vr1[i];
      Vt[dgf +  8 + i][kk] = (_Float16)vr2[i];
      Vt[dgf + 12 + i][kk] = (_Float16)vr3[i];
    }
    __syncthreads();

    // ---- issue prefetch for tile t+1 (lands during compute below) ----
    {
      int tn = (t + 1 < NIT) ? t + 1 : NIT - 1;   // clamp: last iter re-reads
      const float* Kp = K + (size_t)(bh * S_LEN + tn * KVB + kk) * DH + dgf;
      kr0 = *(const f32x4*)(Kp);  kr1 = *(const f32x4*)(Kp + 4);
      kr2 = *(const f32x4*)(Kp + 8); kr3 = *(const f32x4*)(Kp + 12);
      const float* Vp = V + (size_t)(bh * S_LEN + tn * KVB + kk) * DH + dgf;
      vr0 = *(const f32x4*)(Vp);  vr1 = *(const f32x4*)(Vp + 4);
      vr2 = *(const f32x4*)(Vp + 8); vr3 = *(const f32x4*)(Vp + 12);
    }

    // ---- S2 = (2Q) K^T : 16 q-rows x 64 k-cols ----
    f32x4 sc[4];
#pragma unroll
    for (int nt = 0; nt < 4; ++nt) {
      f16x8 kb0 = *(const f16x8*)&Kl[nt * 16 + ln][g * 8];
      f16x8 kb1 = *(const f16x8*)&Kl[nt * 16 + ln][32 + g * 8];
      f32x4 a = (f32x4){0.f, 0.f, 0.f, 0.f};
      a = __builtin_amdgcn_mfma_f32_16x16x32_f16(Qa0, kb0, a, 0, 0, 0);
      a = __builtin_amdgcn_mfma_f32_16x16x32_f16(Qa1, kb1, a, 0, 0, 0);
      sc[nt] = a;
    }

    // ---- dropout (threefry): q = qw+g*4+r, k = t*64+nt*16+ln ----
    float sm[4][4];
#pragma unroll
    for (int nt = 0; nt < 4; ++nt) {
#pragma unroll
      for (int r = 0; r < 4; ++r) {
        unsigned q  = qw + g * 4 + r;
        unsigned kg = (unsigned)t * KVB + nt * 16 + ln;
        unsigned e  = (bh << 20) + (q << 10) + kg;
        sm[nt][r] = keep_bit(e) ? sc[nt][r] : 0.0f;  // already /(1-p)-scaled
      }
    }

    // ---- online softmax over 64 k-cols ----
    float ps[4][4];
#pragma unroll
    for (int r = 0; r < 4; ++r) {
      float mx = fmaxf(fmaxf(sm[0][r], sm[1][r]), fmaxf(sm[2][r], sm[3][r]));
#pragma unroll
      for (int off = 1; off < 16; off <<= 1) mx = fmaxf(mx, __shfl_xor(mx, off));
      float mn  = fmaxf(mrun[r], mx);
      float scl = __expf(mrun[r] - mn);
      mrun[r] = mn;
      float rs = 0.f;
#pragma unroll
      for (int nt = 0; nt < 4; ++nt) {
        float p = __expf(sm[nt][r] - mn);
        ps[nt][r] = p; rs += p;
      }
#pragma unroll
      for (int off = 1; off < 16; off <<= 1) rs += __shfl_xor(rs, off);
      lrun[r] = lrun[r] * scl + rs;
#pragma unroll
      for (int n = 0; n < 4; ++n) accO[n][r] *= scl;
    }

    // ---- P -> wave-private LDS (re-layout for PV A-frag) ----
#pragma unroll
    for (int nt = 0; nt < 4; ++nt)
#pragma unroll
      for (int r = 0; r < 4; ++r)
        Pl[w][g * 4 + r][nt * 16 + ln] = (_Float16)ps[nt][r];

    // ---- O += P V ----
    f16x8 Pa0 = *(const f16x8*)&Pl[w][ln][g * 8];
    f16x8 Pa1 = *(const f16x8*)&Pl[w][ln][32 + g * 8];
#pragma unroll
    for (int nd = 0; nd < 4; ++nd) {
      f16x8 vb0 = *(const f16x8*)&Vt[nd * 16 + ln][g * 8];
      f16x8 vb1 = *(const f16x8*)&Vt[nd * 16 + ln][32 + g * 8];
      accO[nd] = __builtin_amdgcn_mfma_f32_16x16x32_f16(Pa0, vb0, accO[nd], 0, 0, 0);
      accO[nd] = __builtin_amdgcn_mfma_f32_16x16x32_f16(Pa1, vb1, accO[nd], 0, 0, 0);
    }
  }

  // ---- epilogue: O / l ----
#pragma unroll
  for (int nd = 0; nd < 4; ++nd) {
#pragma unroll
    for (int r = 0; r < 4; ++r) {
      unsigned q = qw + g * 4 + r;
      out[(size_t)(bh * S_LEN + q) * DH + nd * 16 + ln] = accO[nd][r] / lrun[r];
    }
  }
}

extern "C" void kernel_launch(void* const* d_in, const int* in_sizes, int n_in,
                              void* d_out, int out_size, void* d_ws, size_t ws_size,
                              hipStream_t stream) {
  const float* Q = (const float*)d_in[0];
  const float* K = (const float*)d_in[1];
  const float* V = (const float*)d_in[2];
  float* out = (float*)d_out;
  dim3 grid(64 * 16);   // (b*16+h) * 16 q-tiles
  dim3 block(256);
  hipLaunchKernelGGL(attn_dropout_kernel, grid, block, 0, stream, Q, K, V, out);
}

// Round 9
// 242.235 us; speedup vs baseline: 1.1891x; 1.0270x over previous
//
#include <hip/hip_runtime.h>
#include <hip/hip_bf16.h>
#include <hip/hip_fp16.h>
#include <math.h>

typedef _Float16 f16x8 __attribute__((ext_vector_type(8)));
typedef __fp16  h16x2 __attribute__((ext_vector_type(2)));
typedef float f32x4 __attribute__((ext_vector_type(4)));

#define S_LEN 1024
#define DH 64
#define KVB 64
#define NIT 16
#define KROW 72   // padded LDS row (elements)
#define THR 11.0f // defer-max threshold (log2 domain): P <= 2^11, fp16-safe

__device__ __forceinline__ unsigned rotl(unsigned x, unsigned r) {
  return __builtin_amdgcn_alignbit(x, x, 32u - r);  // single v_alignbit_b32
}

// JAX threefry2x32, key=(0,42), counts=(0,e) [threefry_partitionable].
// draw = x0 ^ x1; keep = top bit == 0 (uniform < 0.5).
__device__ __forceinline__ bool keep_bit(unsigned e) {
  const unsigned ks1 = 42u;
  const unsigned ks2 = 0x1BD11BF0u;  // 0 ^ 42 ^ 0x1BD11BDA
  unsigned x0 = 0u;
  unsigned x1 = e + ks1;
#define TFR(Ra,Rb,Rc,Rd) \
  x0 += x1; x1 = rotl(x1, Ra); x1 ^= x0; \
  x0 += x1; x1 = rotl(x1, Rb); x1 ^= x0; \
  x0 += x1; x1 = rotl(x1, Rc); x1 ^= x0; \
  x0 += x1; x1 = rotl(x1, Rd); x1 ^= x0;
  TFR(13u,15u,26u, 6u)  x0 += ks1; x1 += ks2 + 1u;
  TFR(17u,29u,16u,24u)  x0 += ks2; x1 += 2u;
  TFR(13u,15u,26u, 6u)  /* +0 */   x1 += ks1 + 3u;
  TFR(17u,29u,16u,24u)  x0 += ks1; x1 += ks2 + 4u;
  TFR(13u,15u,26u, 6u)  x0 += ks2; x1 += 5u;
#undef TFR
  return ((x0 ^ x1) >> 31) == 0u;
}

__device__ __forceinline__ f16x8 pk8(f32x4 a, f32x4 b) {
  h16x2 p0 = __builtin_amdgcn_cvt_pkrtz(a[0], a[1]);
  h16x2 p1 = __builtin_amdgcn_cvt_pkrtz(a[2], a[3]);
  h16x2 p2 = __builtin_amdgcn_cvt_pkrtz(b[0], b[1]);
  h16x2 p3 = __builtin_amdgcn_cvt_pkrtz(b[2], b[3]);
  f16x8 r;
  r[0]=(_Float16)p0[0]; r[1]=(_Float16)p0[1]; r[2]=(_Float16)p1[0]; r[3]=(_Float16)p1[1];
  r[4]=(_Float16)p2[0]; r[5]=(_Float16)p2[1]; r[6]=(_Float16)p3[0]; r[7]=(_Float16)p3[1];
  return r;
}

__global__ __launch_bounds__(256)
void attn_dropout_kernel(const float* __restrict__ Q, const float* __restrict__ K,
                         const float* __restrict__ V, float* __restrict__ out) {
  // One block = one (b,h) x 64 q-rows; 4 waves x 16 q-rows, all 64 k-cols.
  // T14 reg-prefetch; T13 ballot-gated defer-max; deferred cross-lane sum.
  __shared__ _Float16 Kl[KVB][KROW];      // [k][d]
  __shared__ _Float16 Vt[DH][KROW];       // [d][k] transposed
  __shared__ _Float16 Pl[4][16][KROW];    // per-wave P tile

  const unsigned bh   = blockIdx.x >> 4;
  const unsigned q0   = (blockIdx.x & 15u) * 64u;
  const unsigned tid  = threadIdx.x;
  const unsigned w    = tid >> 6;
  const unsigned lane = tid & 63u;
  const unsigned g    = lane >> 4;     // 0..3
  const unsigned ln   = lane & 15u;    // 0..15
  const unsigned qw   = q0 + w * 16u;

  // ---- Q fragments, pre-scaled by 2*log2(e): folds dropout 1/(1-p) AND
  //      the exp->exp2 conversion into QK^T ----
  f16x8 Qa0, Qa1;
  {
    const float* Qp = Q + (size_t)(bh * S_LEN + qw + ln) * DH + g * 8;
    const float s = 2.885390082f;  // 2 * log2(e)
    f32x4 a = *(const f32x4*)(Qp)      * s;
    f32x4 b = *(const f32x4*)(Qp + 4)  * s;
    f32x4 c = *(const f32x4*)(Qp + 32) * s;
    f32x4 d = *(const f32x4*)(Qp + 36) * s;
    Qa0 = pk8(a, b);
    Qa1 = pk8(c, d);
  }

  float mrun[4], lpart[4];
  f32x4 accO[4];
#pragma unroll
  for (int r = 0; r < 4; ++r) { mrun[r] = -1e30f; lpart[r] = 0.0f; }
#pragma unroll
  for (int n = 0; n < 4; ++n) accO[n] = (f32x4){0.f, 0.f, 0.f, 0.f};

  const unsigned kk  = tid >> 2;          // 0..63 staging row
  const unsigned dgf = (tid & 3u) * 16u;  // 16 floats per thread

  // ---- prologue: prefetch tile 0 into registers ----
  f32x4 kr0, kr1, kr2, kr3, vr0, vr1, vr2, vr3;
  {
    const float* Kp = K + (size_t)(bh * S_LEN + kk) * DH + dgf;
    kr0 = *(const f32x4*)(Kp);  kr1 = *(const f32x4*)(Kp + 4);
    kr2 = *(const f32x4*)(Kp + 8); kr3 = *(const f32x4*)(Kp + 12);
    const float* Vp = V + (size_t)(bh * S_LEN + kk) * DH + dgf;
    vr0 = *(const f32x4*)(Vp);  vr1 = *(const f32x4*)(Vp + 4);
    vr2 = *(const f32x4*)(Vp + 8); vr3 = *(const f32x4*)(Vp + 12);
  }

  for (int t = 0; t < NIT; ++t) {
    __syncthreads();   // previous tile fully consumed
    // ---- write staged regs (tile t) to LDS ----
    *(f16x8*)&Kl[kk][dgf]     = pk8(kr0, kr1);
    *(f16x8*)&Kl[kk][dgf + 8] = pk8(kr2, kr3);
#pragma unroll
    for (int i = 0; i < 4; ++i) {
      Vt[dgf +  0 + i][kk] = (_Float16)vr0[i];
      Vt[dgf +  4 + i][kk] = (_Float16)vr1[i];
      Vt[dgf +  8 + i][kk] = (_Float16)vr2[i];
      Vt[dgf + 12 + i][kk] = (_Float16)vr3[i];
    }
    __syncthreads();

    // ---- issue prefetch for tile t+1 (lands during compute below) ----
    {
      int tn = (t + 1 < NIT) ? t + 1 : NIT - 1;   // clamp: last iter re-reads
      const float* Kp = K + (size_t)(bh * S_LEN + tn * KVB + kk) * DH + dgf;
      kr0 = *(const f32x4*)(Kp);  kr1 = *(const f32x4*)(Kp + 4);
      kr2 = *(const f32x4*)(Kp + 8); kr3 = *(const f32x4*)(Kp + 12);
      const float* Vp = V + (size_t)(bh * S_LEN + tn * KVB + kk) * DH + dgf;
      vr0 = *(const f32x4*)(Vp);  vr1 = *(const f32x4*)(Vp + 4);
      vr2 = *(const f32x4*)(Vp + 8); vr3 = *(const f32x4*)(Vp + 12);
    }

    // ---- S2 = (2*log2e*Q) K^T : 16 q-rows x 64 k-cols ----
    f32x4 sc[4];
#pragma unroll
    for (int nt = 0; nt < 4; ++nt) {
      f16x8 kb0 = *(const f16x8*)&Kl[nt * 16 + ln][g * 8];
      f16x8 kb1 = *(const f16x8*)&Kl[nt * 16 + ln][32 + g * 8];
      f32x4 a = (f32x4){0.f, 0.f, 0.f, 0.f};
      a = __builtin_amdgcn_mfma_f32_16x16x32_f16(Qa0, kb0, a, 0, 0, 0);
      a = __builtin_amdgcn_mfma_f32_16x16x32_f16(Qa1, kb1, a, 0, 0, 0);
      sc[nt] = a;
    }

    // ---- dropout (threefry) + per-lane partial row max ----
    float sm[4][4];
    float pmx[4];
#pragma unroll
    for (int r = 0; r < 4; ++r) pmx[r] = -1e30f;
#pragma unroll
    for (int nt = 0; nt < 4; ++nt) {
#pragma unroll
      for (int r = 0; r < 4; ++r) {
        unsigned q  = qw + g * 4 + r;
        unsigned kg = (unsigned)t * KVB + nt * 16 + ln;
        unsigned e  = (bh << 20) + (q << 10) + kg;
        float v = keep_bit(e) ? sc[nt][r] : 0.0f;   // dropped -> 0 (log2 dom.)
        sm[nt][r] = v;
        pmx[r] = fmaxf(pmx[r], v);
      }
    }

    // ---- T13: ballot-gated max update + rescale (rare path) ----
    bool need = (pmx[0] > mrun[0] + THR) | (pmx[1] > mrun[1] + THR) |
                (pmx[2] > mrun[2] + THR) | (pmx[3] > mrun[3] + THR);
    if (__any(need)) {
#pragma unroll
      for (int r = 0; r < 4; ++r) {
        float mx = pmx[r];
#pragma unroll
        for (int off = 1; off < 16; off <<= 1) mx = fmaxf(mx, __shfl_xor(mx, off));
        float mn  = fmaxf(mrun[r], mx);
        float scl = exp2f(mrun[r] - mn);
        mrun[r] = mn;
        lpart[r] *= scl;
#pragma unroll
        for (int n = 0; n < 4; ++n) accO[n][r] *= scl;
      }
    }

    // ---- P = 2^(S - m); per-lane partial sum only (cross-lane deferred) ----
    float ps[4][4];
#pragma unroll
    for (int nt = 0; nt < 4; ++nt) {
#pragma unroll
      for (int r = 0; r < 4; ++r) {
        float p = exp2f(sm[nt][r] - mrun[r]);
        ps[nt][r] = p;
        lpart[r] += p;
      }
    }

    // ---- P -> wave-private LDS (re-layout for PV A-frag) ----
#pragma unroll
    for (int nt = 0; nt < 4; ++nt)
#pragma unroll
      for (int r = 0; r < 4; ++r)
        Pl[w][g * 4 + r][nt * 16 + ln] = (_Float16)ps[nt][r];

    // ---- O += P V ----
    f16x8 Pa0 = *(const f16x8*)&Pl[w][ln][g * 8];
    f16x8 Pa1 = *(const f16x8*)&Pl[w][ln][32 + g * 8];
#pragma unroll
    for (int nd = 0; nd < 4; ++nd) {
      f16x8 vb0 = *(const f16x8*)&Vt[nd * 16 + ln][g * 8];
      f16x8 vb1 = *(const f16x8*)&Vt[nd * 16 + ln][32 + g * 8];
      accO[nd] = __builtin_amdgcn_mfma_f32_16x16x32_f16(Pa0, vb0, accO[nd], 0, 0, 0);
      accO[nd] = __builtin_amdgcn_mfma_f32_16x16x32_f16(Pa1, vb1, accO[nd], 0, 0, 0);
    }
  }

  // ---- epilogue: reduce l across the 16 k-lanes once, then O / l ----
  float lf[4];
#pragma unroll
  for (int r = 0; r < 4; ++r) {
    float l = lpart[r];
#pragma unroll
    for (int off = 1; off < 16; off <<= 1) l += __shfl_xor(l, off);
    lf[r] = l;
  }
#pragma unroll
  for (int nd = 0; nd < 4; ++nd) {
#pragma unroll
    for (int r = 0; r < 4; ++r) {
      unsigned q = qw + g * 4 + r;
      out[(size_t)(bh * S_LEN + q) * DH + nd * 16 + ln] = accO[nd][r] / lf[r];
    }
  }
}

extern "C" void kernel_launch(void* const* d_in, const int* in_sizes, int n_in,
                              void* d_out, int out_size, void* d_ws, size_t ws_size,
                              hipStream_t stream) {
  const float* Q = (const float*)d_in[0];
  const float* K = (const float*)d_in[1];
  const float* V = (const float*)d_in[2];
  float* out = (float*)d_out;
  dim3 grid(64 * 16);   // (b*16+h) * 16 q-tiles
  dim3 block(256);
  hipLaunchKernelGGL(attn_dropout_kernel, grid, block, 0, stream, Q, K, V, out);
}